// Round 7
// baseline (253.153 us; speedup 1.0000x reference)
//
#include <hip/hip_runtime.h>

#define HIDDEN 768
#define NHEAD 12
#define HDIM 64
#define SEQ 512
#define BATCH 32
#define MTOT (BATCH*SEQ)   // 16384

typedef __attribute__((ext_vector_type(8))) short short8;
typedef __attribute__((ext_vector_type(4))) float f32x4;
typedef __attribute__((ext_vector_type(4))) unsigned short us4;

#define LOG2E 1.44269504088896340736f

__device__ __forceinline__ unsigned short f2bf(float f){
  unsigned u = __builtin_bit_cast(unsigned, f);
  u += 0x7fff + ((u >> 16) & 1);   // RNE
  return (unsigned short)(u >> 16);
}

__device__ __forceinline__ void gload16(unsigned short* lds, const unsigned short* g){
  __builtin_amdgcn_global_load_lds(
      (const __attribute__((address_space(1))) void*)g,
      (__attribute__((address_space(3))) void*)lds, 16, 0, 0);
}

// ---------------- fp32 -> bf16 conversion ----------------
__global__ __launch_bounds__(256) void cvt_kernel(const float* __restrict__ in,
                                                  unsigned short* __restrict__ out, int n4){
  int i = blockIdx.x * blockDim.x + threadIdx.x;
  if (i >= n4) return;
  float4 v = ((const float4*)in)[i];
  ushort4 o;
  o.x = f2bf(v.x); o.y = f2bf(v.y); o.z = f2bf(v.z); o.w = f2bf(v.w);
  ((ushort4*)out)[i] = o;
}

__global__ __launch_bounds__(256) void cvt4_kernel(
    const float* __restrict__ w0, const float* __restrict__ w1,
    const float* __restrict__ w2, const float* __restrict__ w3,
    unsigned short* __restrict__ o0, unsigned short* __restrict__ o1,
    unsigned short* __restrict__ o2, unsigned short* __restrict__ o3){
  const int which = blockIdx.y;
  const float* in = (which==0)?w0:((which==1)?w1:((which==2)?w2:w3));
  unsigned short* out = (which==0)?o0:((which==1)?o1:((which==2)?o2:o3));
  int i = blockIdx.x * blockDim.x + threadIdx.x;
  float4 v = ((const float4*)in)[i];
  ushort4 o;
  o.x = f2bf(v.x); o.y = f2bf(v.y); o.z = f2bf(v.z); o.w = f2bf(v.w);
  ((ushort4*)out)[i] = o;
}

// ======== 256x256 GEMM, 24 phases (12 K-tiles x 2 k-halves), 8x16KB LDS ring ========
// 8 waves (2m x 4n), wave tile 128x64. Phase p: read subbufs (2p,2p+1)&7 (12 b128),
// issue stage(p+3) into subbufs read at p-1, 32 MFMA, vmcnt(8) [stages p+2,p+3 in
// flight], ONE barrier. Subbuf layout: slot s -> row (s>>5)*8+(s&7), chunk (s>>3)&3
// (bank-group = row&7, conflict-free). Source addrs permuted to match (rule 21).
#define NPHASE 24

#define STAGE(P_) do { \
    const int kc_ = ((P_) >> 1)*64 + ((P_) & 1)*32; \
    unsigned short* dA_ = &sub[(2*(P_)) & 7][0]; \
    unsigned short* dB_ = &sub[(2*(P_)+1) & 7][0]; \
    gload16(dA_ + (size_t)tid*8,       gA + kc_); \
    gload16(dA_ + (size_t)(512+tid)*8, gA + (size_t)128*HIDDEN + kc_); \
    gload16(dB_ + (size_t)tid*8,       gB + kc_); \
    gload16(dB_ + (size_t)(512+tid)*8, gB + (size_t)128*HIDDEN + kc_); \
  } while(0)

#define GEMM_MAIN() \
  STAGE(0); STAGE(1); STAGE(2); \
  asm volatile("s_waitcnt vmcnt(8)" ::: "memory"); \
  __builtin_amdgcn_s_barrier(); \
  for (int p = 0; p < NPHASE; ++p) { \
    __builtin_amdgcn_sched_barrier(0); \
    const unsigned short* bufA = &sub[(2*p) & 7][0]; \
    const unsigned short* bufB = &sub[(2*p+1) & 7][0]; \
    short8 af[8], bf[4]; \
    _Pragma("unroll") \
    for (int i = 0; i < 8; i++) af[i] = *(const short8*)&bufA[aoff[i]]; \
    _Pragma("unroll") \
    for (int i = 0; i < 4; i++) bf[i] = *(const short8*)&bufB[boff[i]]; \
    if (p + 3 < NPHASE) STAGE(p+3); \
    asm volatile("s_waitcnt lgkmcnt(0)" ::: "memory"); \
    __builtin_amdgcn_sched_barrier(0); \
    __builtin_amdgcn_s_setprio(1); \
    _Pragma("unroll") \
    for (int mi2 = 0; mi2 < 8; mi2++) \
      _Pragma("unroll") \
      for (int ni = 0; ni < 4; ni++) \
        acc[mi2][ni] = __builtin_amdgcn_mfma_f32_16x16x32_bf16(af[mi2], bf[ni], acc[mi2][ni], 0, 0, 0); \
    __builtin_amdgcn_s_setprio(0); \
    __builtin_amdgcn_sched_barrier(0); \
    if (p < NPHASE-3)       asm volatile("s_waitcnt vmcnt(8)" ::: "memory"); \
    else if (p == NPHASE-3) asm volatile("s_waitcnt vmcnt(4)" ::: "memory"); \
    else                    asm volatile("s_waitcnt vmcnt(0)" ::: "memory"); \
    __builtin_amdgcn_s_barrier(); \
  }

// ---------------- QKV GEMM ----------------
__global__ __launch_bounds__(512, 2) void qkv_gemm(
    const unsigned short* __restrict__ A,
    const unsigned short* __restrict__ Wq,
    const unsigned short* __restrict__ Wk,
    const unsigned short* __restrict__ Wv,
    const float* __restrict__ bq,
    const float* __restrict__ bk,
    const float* __restrict__ bv,
    unsigned short* __restrict__ Qo,   // [384][512][64], pre-scaled by 1/8
    unsigned short* __restrict__ Ko,   // [384][512][64]
    unsigned short* __restrict__ VTo)  // [384][64][512]
{
  __shared__ unsigned short sub[8][8192];   // 8 x 16KB ring

  // 576 blocks = 8 XCD x 72; m-major within XCD (A-panel L2 reuse)
  const int flat = blockIdx.x;
  const int swzb = (flat & 7) * 72 + (flat >> 3);
  const int mi_ = swzb / 9;
  const int rem = swzb % 9;
  const int mode = rem / 3;
  const int n0 = (rem % 3) * 256;
  const int m0 = mi_ * 256;
  const unsigned short* W = (mode==0) ? Wq : ((mode==1) ? Wk : Wv);
  const float* bias = (mode==0) ? bq : ((mode==1) ? bk : bv);

  const int tid = threadIdx.x;
  const int lane = tid & 63;
  const int wid = tid >> 6;
  const int wm = wid >> 2, wn = wid & 3;    // 2 x 4 waves
  const int g = lane >> 4, l16 = lane & 15;

  // staging source decode: slot tid -> row (tid>>5)*8+(tid&7), chunk (tid>>3)&3
  const int rS = ((tid >> 5) << 3) + (tid & 7);
  const int cS = (tid >> 3) & 3;
  const unsigned short* gA = &A[(size_t)(m0 + rS)*HIDDEN + cS*8];
  const unsigned short* gB = &W[(size_t)(n0 + rS)*HIDDEN + cS*8];

  // frag read offsets (shorts): row r -> (r>>3)*256 + g*64 + (r&7)*8
  int aoff[8], boff[4];
  #pragma unroll
  for (int i = 0; i < 8; i++){
    int rm = wm*128 + i*16 + l16;
    aoff[i] = ((rm >> 3) << 8) + g*64 + ((rm & 7) << 3);
  }
  #pragma unroll
  for (int i = 0; i < 4; i++){
    int rn = wn*64 + i*16 + l16;
    boff[i] = ((rn >> 3) << 8) + g*64 + ((rn & 7) << 3);
  }

  f32x4 acc[8][4];
  #pragma unroll
  for (int i = 0; i < 8; i++)
    #pragma unroll
    for (int j = 0; j < 4; j++) acc[i][j] = (f32x4){0.f,0.f,0.f,0.f};

  GEMM_MAIN();

  float bvv[4];
  #pragma unroll
  for (int ni = 0; ni < 4; ni++) bvv[ni] = bias[n0 + wn*64 + ni*16 + l16];
  #pragma unroll
  for (int mi2 = 0; mi2 < 8; mi2++) {
    int mbase = m0 + wm*128 + mi2*16 + g*4;
    int b = mbase >> 9, s = mbase & 511;
    #pragma unroll
    for (int ni = 0; ni < 4; ni++) {
      int ncol = n0 + wn*64 + ni*16 + l16;
      int h = ncol >> 6, d = ncol & 63;
      if (mode == 2) {
        us4 v;
        #pragma unroll
        for (int r = 0; r < 4; r++) v[r] = f2bf(acc[mi2][ni][r] + bvv[ni]);
        *(us4*)&VTo[(((size_t)(b*NHEAD)+h)*HDIM + d)*SEQ + s] = v;
      } else {
        #pragma unroll
        for (int r = 0; r < 4; r++) {
          float val = acc[mi2][ni][r] + bvv[ni];
          if (mode == 0) Qo[(((size_t)(b*NHEAD)+h)*SEQ + s + r)*HDIM + d] = f2bf(val * 0.125f);
          else           Ko[(((size_t)(b*NHEAD)+h)*SEQ + s + r)*HDIM + d] = f2bf(val);
        }
      }
    }
  }
}

// ---------------- output projection GEMM ----------------
__global__ __launch_bounds__(512, 2) void proj_gemm(
    const unsigned short* __restrict__ A,   // ctx bf16 [16384][768]
    const unsigned short* __restrict__ W,   // Wo bf16 [768][768]
    const float* __restrict__ bias,
    float* __restrict__ Out)                // fp32 [16384][768]
{
  __shared__ unsigned short sub[8][8192];

  const int flat = blockIdx.x;              // 192 = 8 x 24
  const int swzb = (flat & 7) * 24 + (flat >> 3);
  const int m0 = (swzb / 3) * 256;
  const int n0 = (swzb % 3) * 256;

  const int tid = threadIdx.x;
  const int lane = tid & 63;
  const int wid = tid >> 6;
  const int wm = wid >> 2, wn = wid & 3;
  const int g = lane >> 4, l16 = lane & 15;

  const int rS = ((tid >> 5) << 3) + (tid & 7);
  const int cS = (tid >> 3) & 3;
  const unsigned short* gA = &A[(size_t)(m0 + rS)*HIDDEN + cS*8];
  const unsigned short* gB = &W[(size_t)(n0 + rS)*HIDDEN + cS*8];

  int aoff[8], boff[4];
  #pragma unroll
  for (int i = 0; i < 8; i++){
    int rm = wm*128 + i*16 + l16;
    aoff[i] = ((rm >> 3) << 8) + g*64 + ((rm & 7) << 3);
  }
  #pragma unroll
  for (int i = 0; i < 4; i++){
    int rn = wn*64 + i*16 + l16;
    boff[i] = ((rn >> 3) << 8) + g*64 + ((rn & 7) << 3);
  }

  f32x4 acc[8][4];
  #pragma unroll
  for (int i = 0; i < 8; i++)
    #pragma unroll
    for (int j = 0; j < 4; j++) acc[i][j] = (f32x4){0.f,0.f,0.f,0.f};

  GEMM_MAIN();

  float bvv[4];
  #pragma unroll
  for (int ni = 0; ni < 4; ni++) bvv[ni] = bias[n0 + wn*64 + ni*16 + l16];
  #pragma unroll
  for (int mi2 = 0; mi2 < 8; mi2++) {
    int mbase = m0 + wm*128 + mi2*16 + g*4;
    #pragma unroll
    for (int ni = 0; ni < 4; ni++) {
      int ncol = n0 + wn*64 + ni*16 + l16;
      #pragma unroll
      for (int r = 0; r < 4; r++)
        Out[(size_t)(mbase + r)*HIDDEN + ncol] = acc[mi2][ni][r] + bvv[ni];
    }
  }
}

// ---------------- flash-style attention (unchanged) ----------------
__global__ __launch_bounds__(256) void attn_kernel(
    const unsigned short* __restrict__ Q,    // [384][512][64], pre-scaled
    const unsigned short* __restrict__ K,    // [384][512][64]
    const unsigned short* __restrict__ VT,   // [384][64][512]
    const float* __restrict__ mask,          // [32][512]
    unsigned short* __restrict__ ctx)        // [16384][768] bf16
{
  __shared__ unsigned short sK[8192];
  __shared__ unsigned short sV[8192];
  __shared__ unsigned short P_lds[8*16*68];
  __shared__ float sMask[512];

  const int flat = blockIdx.x;
  const int swzb = (flat & 7) * 192 + (flat >> 3);
  const int qt = swzb & 3;
  const int bh = swzb >> 2;
  const int b = bh / NHEAD, h = bh % NHEAD;
  const int tid = threadIdx.x;
  const int lane = tid & 63;
  const int wid = tid >> 6;
  const int g = lane >> 4, l16 = lane & 15;
  const int qbase = qt*128 + wid*32;

  const int rS = tid >> 3;
  const int cbS = (tid & 7) ^ (rS & 7);
  const size_t khb = (size_t)bh * SEQ;
  const unsigned short* gK  = &K[(khb + rS)*HDIM + cbS*8];
  const unsigned short* gK2 = gK + (size_t)32*HDIM;
  const unsigned short* gV  = &VT[((size_t)bh*HDIM + rS)*SEQ + cbS*8];
  const unsigned short* gV2 = gV + (size_t)32*SEQ;

  sMask[tid]       = mask[b*SEQ + tid];
  sMask[tid + 256] = mask[b*SEQ + tid + 256];

  short8 aQ0[2], aQ1[2];
  #pragma unroll
  for (int q16 = 0; q16 < 2; q16++){
    const unsigned short* qp = &Q[(khb + qbase + q16*16 + l16)*HDIM];
    aQ0[q16] = *(const short8*)&qp[g*8];
    aQ1[q16] = *(const short8*)&qp[32 + g*8];
  }

  int off[4];
  {
    const int sw = (g ^ (l16 & 7)) * 8;
    #pragma unroll
    for (int i = 0; i < 4; i++) off[i] = (i*16 + l16)*64 + sw;
  }

  float m_r[2][4], l_r[2][4];
  f32x4 o_acc[2][4];
  #pragma unroll
  for (int q16 = 0; q16 < 2; q16++){
    #pragma unroll
    for (int r = 0; r < 4; r++){ m_r[q16][r] = -1e30f; l_r[q16][r] = 0.f; }
    #pragma unroll
    for (int dt = 0; dt < 4; dt++) o_acc[q16][dt] = (f32x4){0.f,0.f,0.f,0.f};
  }

  gload16(&sK[wid*512],        gK);
  gload16(&sK[2048 + wid*512], gK2);
  gload16(&sV[wid*512],        gV);
  gload16(&sV[2048 + wid*512], gV2);
  __syncthreads();

  for (int kt = 0; kt < 8; ++kt) {
    const int cur = (kt & 1) * 4096;
    const int kv0 = kt * 64;
    if (kt < 7) {
      const int nxt = 4096 - cur;
      gload16(&sK[nxt + wid*512],        gK  + (size_t)(kv0 + 64)*HDIM);
      gload16(&sK[nxt + 2048 + wid*512], gK2 + (size_t)(kv0 + 64)*HDIM);
      gload16(&sV[nxt + wid*512],        gV  + (kv0 + 64));
      gload16(&sV[nxt + 2048 + wid*512], gV2 + (kv0 + 64));
    }
    const unsigned short* bK = &sK[cur];
    const unsigned short* bV = &sV[cur];

    f32x4 sacc[2][4];
    #pragma unroll
    for (int ct = 0; ct < 4; ++ct) {
      short8 k0 = *(const short8*)&bK[off[ct]];
      short8 k1 = *(const short8*)&bK[off[ct] ^ 32];
      f32x4 s0 = (f32x4){0.f,0.f,0.f,0.f}, s1 = (f32x4){0.f,0.f,0.f,0.f};
      s0 = __builtin_amdgcn_mfma_f32_16x16x32_bf16(aQ0[0], k0, s0, 0, 0, 0);
      s0 = __builtin_amdgcn_mfma_f32_16x16x32_bf16(aQ1[0], k1, s0, 0, 0, 0);
      s1 = __builtin_amdgcn_mfma_f32_16x16x32_bf16(aQ0[1], k0, s1, 0, 0, 0);
      s1 = __builtin_amdgcn_mfma_f32_16x16x32_bf16(aQ1[1], k1, s1, 0, 0, 0);
      float mv = sMask[kv0 + ct*16 + l16];
      sacc[0][ct] = s0 + mv;
      sacc[1][ct] = s1 + mv;
    }

    #pragma unroll
    for (int q16 = 0; q16 < 2; q16++){
      float tm[4];
      #pragma unroll
      for (int r = 0; r < 4; r++)
        tm[r] = fmaxf(fmaxf(sacc[q16][0][r], sacc[q16][1][r]), fmaxf(sacc[q16][2][r], sacc[q16][3][r]));
      #pragma unroll
      for (int o = 1; o <= 8; o <<= 1){
        #pragma unroll
        for (int r = 0; r < 4; r++) tm[r] = fmaxf(tm[r], __shfl_xor(tm[r], o));
      }
      #pragma unroll
      for (int r = 0; r < 4; r++){
        float mnew = fmaxf(m_r[q16][r], tm[r]);
        float sc = exp2f((m_r[q16][r] - mnew) * LOG2E);
        m_r[q16][r] = mnew;
        l_r[q16][r] *= sc;
        #pragma unroll
        for (int dt = 0; dt < 4; dt++) o_acc[q16][dt][r] *= sc;
      }
      #pragma unroll
      for (int ct = 0; ct < 4; ct++){
        #pragma unroll
        for (int r = 0; r < 4; r++){
          float p = exp2f((sacc[q16][ct][r] - m_r[q16][r]) * LOG2E);
          l_r[q16][r] += p;
          P_lds[((wid*2 + q16)*16 + g*4 + r)*68 + ct*16 + l16] = f2bf(p);
        }
      }
    }
    asm volatile("s_waitcnt lgkmcnt(0)" ::: "memory");

    short8 pa0[2], pa1[2];
    #pragma unroll
    for (int q16 = 0; q16 < 2; q16++){
      pa0[q16] = *(const short8*)&P_lds[((wid*2 + q16)*16 + l16)*68 + g*8];
      pa1[q16] = *(const short8*)&P_lds[((wid*2 + q16)*16 + l16)*68 + 32 + g*8];
    }
    #pragma unroll
    for (int dt = 0; dt < 4; dt++){
      short8 v0 = *(const short8*)&bV[off[dt]];
      short8 v1 = *(const short8*)&bV[off[dt] ^ 32];
      o_acc[0][dt] = __builtin_amdgcn_mfma_f32_16x16x32_bf16(pa0[0], v0, o_acc[0][dt], 0, 0, 0);
      o_acc[0][dt] = __builtin_amdgcn_mfma_f32_16x16x32_bf16(pa1[0], v1, o_acc[0][dt], 0, 0, 0);
      o_acc[1][dt] = __builtin_amdgcn_mfma_f32_16x16x32_bf16(pa0[1], v0, o_acc[1][dt], 0, 0, 0);
      o_acc[1][dt] = __builtin_amdgcn_mfma_f32_16x16x32_bf16(pa1[1], v1, o_acc[1][dt], 0, 0, 0);
    }
    __syncthreads();
  }

  #pragma unroll
  for (int q16 = 0; q16 < 2; q16++){
    #pragma unroll
    for (int o = 1; o <= 8; o <<= 1){
      #pragma unroll
      for (int r = 0; r < 4; r++) l_r[q16][r] += __shfl_xor(l_r[q16][r], o);
    }
    float inv[4];
    #pragma unroll
    for (int r = 0; r < 4; r++) inv[r] = 1.f / l_r[q16][r];
    #pragma unroll
    for (int dt = 0; dt < 4; dt++){
      #pragma unroll
      for (int r = 0; r < 4; r++){
        int s = qbase + q16*16 + g*4 + r;
        ctx[((size_t)(b*SEQ + s))*HIDDEN + h*HDIM + dt*16 + l16] = f2bf(o_acc[q16][dt][r] * inv[r]);
      }
    }
  }
}

// ---------------- residual + LayerNorm ----------------
__global__ __launch_bounds__(256) void resid_ln(
    const float* __restrict__ x, const float* __restrict__ ao,
    const float* __restrict__ lnw, const float* __restrict__ lnb,
    float* __restrict__ out)
{
  const int row = blockIdx.x*4 + (threadIdx.x >> 6);
  const int lane = threadIdx.x & 63;
  const float4* xr = (const float4*)&x[(size_t)row*HIDDEN];
  const float4* ar = (const float4*)&ao[(size_t)row*HIDDEN];
  float4 y[3];
  float s1 = 0.f, s2 = 0.f;
  #pragma unroll
  for (int j = 0; j < 3; j++){
    float4 xv = xr[lane + j*64];
    float4 av = ar[lane + j*64];
    float4 v;
    v.x = xv.x + av.x; v.y = xv.y + av.y; v.z = xv.z + av.z; v.w = xv.w + av.w;
    y[j] = v;
    s1 += v.x + v.y + v.z + v.w;
    s2 += v.x*v.x + v.y*v.y + v.z*v.z + v.w*v.w;
  }
  #pragma unroll
  for (int o = 1; o <= 32; o <<= 1){
    s1 += __shfl_xor(s1, o);
    s2 += __shfl_xor(s2, o);
  }
  float mean = s1 * (1.f/768.f);
  float var = s2 * (1.f/768.f) - mean*mean;
  float rstd = rsqrtf(var + 1e-12f);
  float4* orow = (float4*)&out[(size_t)row*HIDDEN];
  #pragma unroll
  for (int j = 0; j < 3; j++){
    float4 gm = ((const float4*)lnw)[lane + j*64];
    float4 bt = ((const float4*)lnb)[lane + j*64];
    float4 o;
    o.x = (y[j].x - mean)*rstd*gm.x + bt.x;
    o.y = (y[j].y - mean)*rstd*gm.y + bt.y;
    o.z = (y[j].z - mean)*rstd*gm.z + bt.z;
    o.w = (y[j].w - mean)*rstd*gm.w + bt.w;
    orow[lane + j*64] = o;
  }
}

extern "C" void kernel_launch(void* const* d_in, const int* in_sizes, int n_in,
                              void* d_out, int out_size, void* d_ws, size_t ws_size,
                              hipStream_t stream) {
  (void)in_sizes; (void)n_in; (void)out_size; (void)ws_size;
  const float* x    = (const float*)d_in[0];
  const float* mask = (const float*)d_in[1];
  const float* Wq   = (const float*)d_in[2];
  const float* bq   = (const float*)d_in[3];
  const float* Wk   = (const float*)d_in[4];
  const float* bk   = (const float*)d_in[5];
  const float* Wv   = (const float*)d_in[6];
  const float* bv   = (const float*)d_in[7];
  const float* Wo   = (const float*)d_in[8];
  const float* bo   = (const float*)d_in[9];
  const float* lnw  = (const float*)d_in[10];
  const float* lnb  = (const float*)d_in[11];
  float* out = (float*)d_out;

  char* w = (char*)d_ws;
  size_t off = 0;
  auto alloc = [&](size_t bytes) -> char* {
    char* p = w + off; off += (bytes + 255) & ~(size_t)255; return p;
  };
  unsigned short* xb  = (unsigned short*)alloc((size_t)MTOT*HIDDEN*2);
  unsigned short* wqb = (unsigned short*)alloc((size_t)HIDDEN*HIDDEN*2);
  unsigned short* wkb = (unsigned short*)alloc((size_t)HIDDEN*HIDDEN*2);
  unsigned short* wvb = (unsigned short*)alloc((size_t)HIDDEN*HIDDEN*2);
  unsigned short* wob = (unsigned short*)alloc((size_t)HIDDEN*HIDDEN*2);
  unsigned short* qb  = (unsigned short*)alloc((size_t)MTOT*HDIM*NHEAD*2);
  unsigned short* kb  = (unsigned short*)alloc((size_t)MTOT*HDIM*NHEAD*2);
  unsigned short* vtb = (unsigned short*)alloc((size_t)MTOT*HDIM*NHEAD*2);
  unsigned short* ctxb= (unsigned short*)alloc((size_t)MTOT*HIDDEN*2);
  float* attn_out = (float*)qb;   // reuses dead q+k region

  cvt_kernel<<<dim3(MTOT*HIDDEN/4/256), 256, 0, stream>>>(x, xb, MTOT*HIDDEN/4);
  cvt4_kernel<<<dim3(HIDDEN*HIDDEN/4/256, 4), 256, 0, stream>>>(Wq, Wk, Wv, Wo, wqb, wkb, wvb, wob);

  qkv_gemm<<<dim3(576), 512, 0, stream>>>(xb, wqb, wkb, wvb, bq, bk, bv, qb, kb, vtb);

  attn_kernel<<<dim3(1536), 256, 0, stream>>>(qb, kb, vtb, mask, ctxb);

  proj_gemm<<<dim3(192), 512, 0, stream>>>(ctxb, wob, bo, attn_out);

  resid_ln<<<dim3(MTOT/4), 256, 0, stream>>>(x, attn_out, lnw, lnb, out);
}